// Round 23
// baseline (185.109 us; speedup 1.0000x reference)
//
#include <hip/hip_runtime.h>
#include <hip/hip_bf16.h>

#define DEVI __device__ __forceinline__

constexpr int Bc = 2, Cc = 64, Tc = 4, Hc = 64, Wc = 64, OFFc = 54, KVc = 27;
constexpr int HW  = Hc * Wc;     // 4096
constexpr int THW = Tc * HW;     // 16384

typedef __attribute__((ext_vector_type(8))) short bf16x8;
typedef __attribute__((ext_vector_type(4))) float f32x4;

DEVI short f2bf(float f) {
    __hip_bfloat16 h = __float2bfloat16(f);
    return *reinterpret_cast<short*>(&h);
}
DEVI float bf2f(short s) {
    unsigned u = ((unsigned)(unsigned short)s) << 16;
    float f; __builtin_memcpy(&f, &u, 4); return f;
}

// ------- all 4 weight buffers -> K-major MFMA A layout, one dispatch -------
__global__ __launch_bounds__(256) void w_prep4(
    const float* __restrict__ w0, const float* __restrict__ w1,
    const float* __restrict__ w2, const float* __restrict__ w3,
    __hip_bfloat16* __restrict__ d0, __hip_bfloat16* __restrict__ d1,
    __hip_bfloat16* __restrict__ d2, __hip_bfloat16* __restrict__ d3)
{
    int gi = blockIdx.x;
    int seg = gi / 432;
    int i = (gi - seg * 432) * 256 + threadIdx.x;   // 216*512 = 110592
    if (i >= 216 * 512) return;
    const float* w = seg == 0 ? w0 : seg == 1 ? w1 : seg == 2 ? w2 : w3;
    __hip_bfloat16* dst = seg == 0 ? d0 : seg == 1 ? d1 : seg == 2 ? d2 : d3;
    int ovalid = (seg < 2) ? OFFc : Cc;
    int u = i >> 9, r = i & 511;
    int mf = u & 3, ch = (u >> 2) & 1, tap = u >> 3;
    int o = mf * 16 + (r >> 5), c = ch * 32 + (r & 31);
    float v = (o < ovalid) ? w[(o * Cc + c) * KVc + tap] : 0.f;
    dst[i] = __float2bfloat16(v);
}

// ------- cast + transpose to channel-last bf16 -------
__global__ __launch_bounds__(256) void cast_cl(const float* __restrict__ x,
                                               __hip_bfloat16* __restrict__ xcl) {
    __shared__ float s[64][65];
    int tid = threadIdx.x;
    int bi  = blockIdx.x;
    int h = bi & 63, t = (bi >> 6) & 3, b = bi >> 8;

    const float* xp = x + (size_t)b * Cc * THW + t * HW + h * 64;
    int w0 = tid & 63, c0 = tid >> 6;
    #pragma unroll
    for (int i = 0; i < 16; ++i) {
        int c = c0 + i * 4;
        s[c][w0] = xp[(size_t)c * THW + w0];
    }
    __syncthreads();

    __hip_bfloat16* dst = xcl + (((size_t)b * Tc + t) * HW + (size_t)h * 64) * 64;
    #pragma unroll
    for (int r = 0; r < 2; ++r) {
        int j  = tid + r * 256;
        int w  = j >> 3;
        int c8 = j & 7;
        bf16x8 v;
        #pragma unroll
        for (int jj = 0; jj < 8; ++jj)
            v[jj] = f2bf(s[c8 * 8 + jj][w]);
        *reinterpret_cast<bf16x8*>(dst + w * 64 + c8 * 8) = v;
    }
}

// ================= fused offset-conv + deformable-conv (R18-proven best) =============
// block = (b,t,h,whalf): 32 positions, 256 thr = 4 waves = nf(2) x chh(2).
// Balanced adjacent-t pairing per XCD: t-pairs {0,1}/{2,3} of one b per XCD-pair,
// tsel=(idx^idx>>5)&1 interleaves light(18-tap)/heavy(27-tap) blocks per CU
// (90 taps/CU balanced); 3-plane slab + w-half stays L2-local (FETCH ~9.4MB).
constexpr int WT = 40;            // tile w-columns, covers global w in [wb-3, wb+36]
constexpr int RSTRIDE = WT * 128; // 5120 bytes per tile row

template <bool L2>
__global__ __launch_bounds__(256, 4) void fused_deform(
    const __hip_bfloat16* __restrict__ src, const __hip_bfloat16* __restrict__ owAk,
    const float* __restrict__ obias, const __hip_bfloat16* __restrict__ wAk,
    const float* __restrict__ xres, float* __restrict__ outf,
    __hip_bfloat16* __restrict__ ycl)
{
    __shared__ __align__(16) char s_mem[5 * RSTRIDE + 7344];
    short* s_tile = (short*)s_mem;                    // swizzled tile
    float* s_off  = (float*)(s_mem + 5 * RSTRIDE);    // [27][2][34]
    float* s_red  = (float*)s_mem;                    // aliased after pass B: [32][68]

    int tid = threadIdx.x;
    int wv = tid >> 6, lane = tid & 63, l15 = lane & 15, l4 = lane >> 4;
    int nf = wv & 1, chh = wv >> 1;

    // ---- balanced plane-pair -> XCD decode ----
    int bi = blockIdx.x;
    int xcd = bi & 7, idx = bi >> 3;          // xcd: HW round-robin target
    int jgrp = xcd >> 1, whalf = xcd & 1;     // job = (b, t-pair); w-half per XCD
    int b = jgrp >> 1;
    int h = idx >> 1;
    int tsel = (idx ^ (idx >> 5)) & 1;        // per-CU light/heavy interleave
    int t = ((jgrp & 1) << 1) + tsel;         // t-pair {0,1} or {2,3}
    int wb = whalf * 32;

    int pl = nf * 16 + l15;               // local position 0..31
    int p  = wb + pl;                     // global w position
    int cbase = chh * 32 + l4 * 8;        // channel slice (MFMA K slice)
    int ktlo = (t == 0) ? 1 : 0, kthi = (t == 3) ? 2 : 3;

    // init s_off with bias (pad cols junk; never read)
    for (int i = tid; i < KVc * 2 * 34; i += 256) {
        int k = i / 68, rem = i - k * 68, jo = rem / 34;
        ((float*)s_off)[i] = obias[2 * k + jo];
    }

    const __hip_bfloat16* xb = src + ((size_t)b << 20);

    auto stage = [&](int kt) {
        int tt = t + kt - 1;   // valid by loop range
        const __hip_bfloat16* xt = xb + ((size_t)tt << 18);
        for (int i = tid; i < 5 * WT * 8; i += 256) {
            int r = i / (WT * 8), v = i - r * (WT * 8);
            int wl = v >> 3, ss = v & 7;
            int hh = h - 2 + r;
            int wg = wb - 3 + wl;
            bf16x8 val = {0, 0, 0, 0, 0, 0, 0, 0};
            if ((unsigned)hh < 64u && (unsigned)wg < 64u)
                val = *reinterpret_cast<const bf16x8*>(xt + ((hh * 64 + wg) << 6) + ss * 8);
            int byte = (r * RSTRIDE + wl * 128 + ss * 16) ^ ((wl & 7) << 4);
            *reinterpret_cast<bf16x8*>((char*)s_tile + byte) = val;
        }
    };
    auto ldread = [&](int sl, int wg) -> bf16x8 {   // wg = clamped global w (in window)
        int wl = wg - (wb - 3);
        int byte = (sl * RSTRIDE + wl * 128 + cbase * 2) ^ ((wl & 7) << 4);
        return *reinterpret_cast<const bf16x8*>((const char*)s_tile + byte);
    };

    // ================= pass A: offset conv (rolled taps) =================
    f32x4 cacc[4];
    #pragma unroll
    for (int mf = 0; mf < 4; ++mf) cacc[mf] = (f32x4){0.f, 0.f, 0.f, 0.f};

    for (int kt = ktlo; kt < kthi; ++kt) {
        __syncthreads();
        stage(kt);
        __syncthreads();
        #pragma clang loop unroll(disable)
        for (int rr = 0; rr < 9; ++rr) {
            int kh = rr / 3, kw = rr - kh * 3, tap = kt * 9 + rr;
            int ws = p + kw - 1;
            int wsc = min(max(ws, 0), 63);
            bf16x8 bv = ldread(kh + 1, wsc);
            if ((unsigned)ws >= 64u) bv = (bf16x8){0, 0, 0, 0, 0, 0, 0, 0};
            const __hip_bfloat16* ab = owAk + ((tap * 2 + chh) << 11) + (l15 << 5) + (l4 << 3);
            #pragma unroll
            for (int mf = 0; mf < 4; ++mf) {
                bf16x8 af = *reinterpret_cast<const bf16x8*>(ab + (mf << 9));
                cacc[mf] = __builtin_amdgcn_mfma_f32_16x16x32_bf16(af, bv, cacc[mf], 0, 0, 0);
            }
        }
    }
    #pragma unroll
    for (int mf = 0; mf < 4; ++mf)
        #pragma unroll
        for (int jj = 0; jj < 4; ++jj) {
            int o = mf * 16 + l4 * 4 + jj;
            if (o < OFFc) atomicAdd(&s_off[(o >> 1) * 68 + (o & 1) * 34 + pl], cacc[mf][jj]);
        }

    // ================= pass B: deformable conv (rolled x2, reverse kt) =================
    f32x4 dacc[4];
    #pragma unroll
    for (int mf = 0; mf < 4; ++mf) dacc[mf] = (f32x4){0.f, 0.f, 0.f, 0.f};

    unsigned badmask = 0;

    for (int kt = kthi - 1; kt >= ktlo; --kt) {
        __syncthreads();     // first iter: guards s_off atomics; tile already holds kthi-1
        if (kt != kthi - 1) {
            stage(kt);
            __syncthreads();
        }
        #pragma clang loop unroll_count(2)
        for (int rr = 0; rr < 9; ++rr) {
            int kh = rr / 3, kw = rr - kh * 3, tap = kt * 9 + rr;
            float dh = s_off[tap * 68 + pl];
            float dw = s_off[tap * 68 + 34 + pl];
            float hs  = (float)(h + kh - 1) + dh;
            float wsf = (float)(p + kw - 1) + dw;
            float fh = floorf(hs), fw = floorf(wsf);
            int h0 = (int)fh, w0 = (int)fw;
            float lh = hs - fh, lw = wsf - fw;
            float q0 = (1.f - lw) * (((unsigned)w0 < 64u) ? 1.f : 0.f);
            float q1 = lw         * (((unsigned)(w0 + 1) < 64u) ? 1.f : 0.f);
            int wc0 = min(max(w0, 0), 63), wc1 = min(max(w0 + 1, 0), 63);
            int r0 = h0 - (h - 2);
            int r0c = min(max(r0, 0), 3);
            badmask |= ((r0 != r0c) ? 1u : 0u) << tap;
            bf16x8 g0 = ldread(r0c, wc0),     g1 = ldread(r0c, wc1);
            bf16x8 g2 = ldread(r0c + 1, wc0), g3 = ldread(r0c + 1, wc1);
            float cf0 = (1.f - lh) * q0, cf1 = (1.f - lh) * q1;
            float cf2 = lh * q0,         cf3 = lh * q1;
            bf16x8 bfrag;
            #pragma unroll
            for (int jj = 0; jj < 8; ++jj) {
                float s = cf0 * bf2f(g0[jj]) + cf1 * bf2f(g1[jj])
                        + cf2 * bf2f(g2[jj]) + cf3 * bf2f(g3[jj]);
                bfrag[jj] = f2bf(s);
            }
            const __hip_bfloat16* ab = wAk + ((tap * 2 + chh) << 11) + (l15 << 5) + (l4 << 3);
            #pragma unroll
            for (int mf = 0; mf < 4; ++mf) {
                bf16x8 af = *reinterpret_cast<const bf16x8*>(ab + (mf << 9));
                dacc[mf] = __builtin_amdgcn_mfma_f32_16x16x32_bf16(af, bfrag, dacc[mf], 0, 0, 0);
            }
        }
    }

    // ---- exact correction for window misses (cold; never taken for ~0.02-scale offsets) ----
    if (__any((int)(badmask != 0u))) {
        for (int kt = ktlo; kt < kthi; ++kt) {
            int tt = t + kt - 1;
            const __hip_bfloat16* xt = xb + ((size_t)tt << 18);
            #pragma clang loop unroll(disable)
            for (int rr = 0; rr < 9; ++rr) {
                int tap = kt * 9 + rr;
                if (!__any((int)((badmask >> tap) & 1u))) continue;
                int kh = rr / 3, kw = rr - kh * 3;
                float dh = s_off[tap * 68 + pl];
                float dw = s_off[tap * 68 + 34 + pl];
                float hs  = (float)(h + kh - 1) + dh;
                float wsf = (float)(p + kw - 1) + dw;
                float fh = floorf(hs), fw = floorf(wsf);
                int h0 = (int)fh, w0 = (int)fw;
                float lh = hs - fh, lw = wsf - fw;
                float q0 = (1.f - lw) * (((unsigned)w0 < 64u) ? 1.f : 0.f);
                float q1 = lw         * (((unsigned)(w0 + 1) < 64u) ? 1.f : 0.f);
                int wc0 = min(max(w0, 0), 63), wc1 = min(max(w0 + 1, 0), 63);
                int r0 = h0 - (h - 2);
                int r0c = min(max(r0, 0), 3);
                bool bad = ((badmask >> tap) & 1u) != 0u;
                float u0 = (1.f - lh) * (((unsigned)h0 < 64u) ? 1.f : 0.f);
                float u1 = lh         * (((unsigned)(h0 + 1) < 64u) ? 1.f : 0.f);
                int hc0 = min(max(h0, 0), 63), hc1 = min(max(h0 + 1, 0), 63);
                bf16x8 tg0 = *reinterpret_cast<const bf16x8*>(xt + ((hc0 * 64 + wc0) << 6) + cbase);
                bf16x8 tg1 = *reinterpret_cast<const bf16x8*>(xt + ((hc0 * 64 + wc1) << 6) + cbase);
                bf16x8 tg2 = *reinterpret_cast<const bf16x8*>(xt + ((hc1 * 64 + wc0) << 6) + cbase);
                bf16x8 tg3 = *reinterpret_cast<const bf16x8*>(xt + ((hc1 * 64 + wc1) << 6) + cbase);
                int ra0 = h - 2 + r0c, ra1 = ra0 + 1;
                float m0 = ((unsigned)ra0 < 64u) ? 1.f : 0.f;
                float m1 = ((unsigned)ra1 < 64u) ? 1.f : 0.f;
                int rc0 = min(max(ra0, 0), 63), rc1 = min(max(ra1, 0), 63);
                bf16x8 ag0 = *reinterpret_cast<const bf16x8*>(xt + ((rc0 * 64 + wc0) << 6) + cbase);
                bf16x8 ag1 = *reinterpret_cast<const bf16x8*>(xt + ((rc0 * 64 + wc1) << 6) + cbase);
                bf16x8 ag2 = *reinterpret_cast<const bf16x8*>(xt + ((rc1 * 64 + wc0) << 6) + cbase);
                bf16x8 ag3 = *reinterpret_cast<const bf16x8*>(xt + ((rc1 * 64 + wc1) << 6) + cbase);
                bf16x8 bfrag;
                #pragma unroll
                for (int jj = 0; jj < 8; ++jj) {
                    float ft = u0 * (q0 * bf2f(tg0[jj]) + q1 * bf2f(tg1[jj]))
                             + u1 * (q0 * bf2f(tg2[jj]) + q1 * bf2f(tg3[jj]));
                    float fa = (1.f - lh) * m0 * (q0 * bf2f(ag0[jj]) + q1 * bf2f(ag1[jj]))
                             + lh * m1 * (q0 * bf2f(ag2[jj]) + q1 * bf2f(ag3[jj]));
                    bfrag[jj] = f2bf(bad ? (ft - fa) : 0.f);
                }
                const __hip_bfloat16* ab = wAk + ((tap * 2 + chh) << 11) + (l15 << 5) + (l4 << 3);
                #pragma unroll
                for (int mf = 0; mf < 4; ++mf) {
                    bf16x8 af = *reinterpret_cast<const bf16x8*>(ab + (mf << 9));
                    dacc[mf] = __builtin_amdgcn_mfma_f32_16x16x32_bf16(af, bfrag, dacc[mf], 0, 0, 0);
                }
            }
        }
    }

    // ---- reduce: s_red aliased onto tile ----
    __syncthreads();
    for (int i = tid; i < 32 * 68; i += 256) s_red[i] = 0.f;
    __syncthreads();
    #pragma unroll
    for (int mf = 0; mf < 4; ++mf)
        #pragma unroll
        for (int jj = 0; jj < 4; ++jj) {
            int o = mf * 16 + l4 * 4 + jj;
            atomicAdd(&s_red[pl * 68 + o], dacc[mf][jj]);
        }
    __syncthreads();

    // ---- fused epilogue ----
    if (!L2) {
        // leaky-relu + channel-last bf16 store (32 pos x 64 ch)
        int pp = tid >> 3, o8 = (tid & 7) << 3;
        __hip_bfloat16* dst = ycl + ((((size_t)b * Tc + t) * HW + h * 64 + wb + pp) << 6) + o8;
        bf16x8 o8v;
        #pragma unroll
        for (int jj = 0; jj < 8; ++jj) {
            float v = s_red[pp * 68 + o8 + jj];
            v = v >= 0.f ? v : 0.1f * v;
            o8v[jj] = f2bf(v);
        }
        *reinterpret_cast<bf16x8*>(dst) = o8v;
    } else {
        // residual add + fp32 channel-first store
        int o = tid >> 2, pg = (tid & 3) << 3;
        size_t base = ((size_t)(b * Cc + o) * Tc + t) * HW + h * 64 + wb + pg;
        #pragma unroll
        for (int q = 0; q < 2; ++q) {
            f32x4 r, xv = *reinterpret_cast<const f32x4*>(xres + base + q * 4);
            #pragma unroll
            for (int jj = 0; jj < 4; ++jj) r[jj] = s_red[(pg + q * 4 + jj) * 68 + o] + xv[jj];
            *reinterpret_cast<f32x4*>(outf + base + q * 4) = r;
        }
    }
}

extern "C" void kernel_launch(void* const* d_in, const int* in_sizes, int n_in,
                              void* d_out, int out_size, void* d_ws, size_t ws_size,
                              hipStream_t stream)
{
    const float* x   = (const float*)d_in[0];
    const float* w0  = (const float*)d_in[1];
    const float* ow0 = (const float*)d_in[2];
    const float* ob0 = (const float*)d_in[3];
    const float* w1  = (const float*)d_in[4];
    const float* ow1 = (const float*)d_in[5];
    const float* ob1 = (const float*)d_in[6];
    float* out = (float*)d_out;

    __hip_bfloat16* xcl  = (__hip_bfloat16*)d_ws;
    __hip_bfloat16* ycl  = xcl  + (size_t)Bc * THW * 64;
    __hip_bfloat16* owA0 = ycl  + (size_t)Bc * THW * 64;
    __hip_bfloat16* owA1 = owA0 + (size_t)216 * 512;
    __hip_bfloat16* wA0  = owA1 + (size_t)216 * 512;
    __hip_bfloat16* wA1  = wA0  + (size_t)216 * 512;

    w_prep4<<<1728, 256, 0, stream>>>(ow0, ow1, w0, w1, owA0, owA1, wA0, wA1);
    cast_cl<<<512, 256, 0, stream>>>(x, xcl);

    fused_deform<false><<<1024, 256, 0, stream>>>(xcl, owA0, ob0, wA0, nullptr, nullptr, ycl);
    fused_deform<true><<<1024, 256, 0, stream>>>(ycl, owA1, ob1, wA1, x, out, nullptr);
}

// Round 24
// 184.095 us; speedup vs baseline: 1.0055x; 1.0055x over previous
//
#include <hip/hip_runtime.h>
#include <hip/hip_bf16.h>

#define DEVI __device__ __forceinline__

constexpr int Bc = 2, Cc = 64, Tc = 4, Hc = 64, Wc = 64, OFFc = 54, KVc = 27;
constexpr int HW  = Hc * Wc;     // 4096
constexpr int THW = Tc * HW;     // 16384

typedef __attribute__((ext_vector_type(8))) short bf16x8;
typedef __attribute__((ext_vector_type(4))) float f32x4;

DEVI short f2bf(float f) {
    __hip_bfloat16 h = __float2bfloat16(f);
    return *reinterpret_cast<short*>(&h);
}
DEVI float bf2f(short s) {
    unsigned u = ((unsigned)(unsigned short)s) << 16;
    float f; __builtin_memcpy(&f, &u, 4); return f;
}

// ------- all 4 weight buffers -> K-major MFMA A layout, one dispatch -------
__global__ __launch_bounds__(256) void w_prep4(
    const float* __restrict__ w0, const float* __restrict__ w1,
    const float* __restrict__ w2, const float* __restrict__ w3,
    __hip_bfloat16* __restrict__ d0, __hip_bfloat16* __restrict__ d1,
    __hip_bfloat16* __restrict__ d2, __hip_bfloat16* __restrict__ d3)
{
    int gi = blockIdx.x;
    int seg = gi / 432;
    int i = (gi - seg * 432) * 256 + threadIdx.x;   // 216*512 = 110592
    if (i >= 216 * 512) return;
    const float* w = seg == 0 ? w0 : seg == 1 ? w1 : seg == 2 ? w2 : w3;
    __hip_bfloat16* dst = seg == 0 ? d0 : seg == 1 ? d1 : seg == 2 ? d2 : d3;
    int ovalid = (seg < 2) ? OFFc : Cc;
    int u = i >> 9, r = i & 511;
    int mf = u & 3, ch = (u >> 2) & 1, tap = u >> 3;
    int o = mf * 16 + (r >> 5), c = ch * 32 + (r & 31);
    float v = (o < ovalid) ? w[(o * Cc + c) * KVc + tap] : 0.f;
    dst[i] = __float2bfloat16(v);
}

// ------- cast + transpose to channel-last bf16 -------
__global__ __launch_bounds__(256) void cast_cl(const float* __restrict__ x,
                                               __hip_bfloat16* __restrict__ xcl) {
    __shared__ float s[64][65];
    int tid = threadIdx.x;
    int bi  = blockIdx.x;
    int h = bi & 63, t = (bi >> 6) & 3, b = bi >> 8;

    const float* xp = x + (size_t)b * Cc * THW + t * HW + h * 64;
    int w0 = tid & 63, c0 = tid >> 6;
    #pragma unroll
    for (int i = 0; i < 16; ++i) {
        int c = c0 + i * 4;
        s[c][w0] = xp[(size_t)c * THW + w0];
    }
    __syncthreads();

    __hip_bfloat16* dst = xcl + (((size_t)b * Tc + t) * HW + (size_t)h * 64) * 64;
    #pragma unroll
    for (int r = 0; r < 2; ++r) {
        int j  = tid + r * 256;
        int w  = j >> 3;
        int c8 = j & 7;
        bf16x8 v;
        #pragma unroll
        for (int jj = 0; jj < 8; ++jj)
            v[jj] = f2bf(s[c8 * 8 + jj][w]);
        *reinterpret_cast<bf16x8*>(dst + w * 64 + c8 * 8) = v;
    }
}

// ========= fused offset-conv + deformable-conv, 2-output-row blocks (stage-amortized) =========
// block = (b,t,h-pair,whalf): 64 positions = 2h x 32w, 512 thr = 8 waves = nf(4) x chh(2).
// Tile [6 rows][40 wcols] serves TWO output rows: staged bytes/output x0.6, barrier
// rounds/output x0.5 vs R18. Balanced adjacent-t pairing per XCD kept (tsel=(idx>>5)&1:
// each CU gets 1 light + 1 heavy block). 512 blocks = 2/CU = 16 waves/CU (same as R18).
constexpr int WT = 40;            // tile w-columns, covers global w in [wb-3, wb+36]
constexpr int RSTRIDE = WT * 128; // 5120 bytes per tile row

template <bool L2>
__global__ __launch_bounds__(512, 2) void fused_deform(
    const __hip_bfloat16* __restrict__ src, const __hip_bfloat16* __restrict__ owAk,
    const float* __restrict__ obias, const __hip_bfloat16* __restrict__ wAk,
    const float* __restrict__ xres, float* __restrict__ outf,
    __hip_bfloat16* __restrict__ ycl)
{
    __shared__ __align__(16) char s_mem[6 * RSTRIDE + 14256];
    short* s_tile = (short*)s_mem;                    // swizzled tile [6][40][64ch]
    float* s_off  = (float*)(s_mem + 6 * RSTRIDE);    // [27][2][66] f32
    float* s_red  = (float*)s_mem;                    // aliased after pass B: [64][68]

    int tid = threadIdx.x;
    int wv = tid >> 6, lane = tid & 63, l15 = lane & 15, l4 = lane >> 4;
    int nf = wv & 3, chh = wv >> 2;

    // ---- balanced plane-pair -> XCD decode ----
    int bi = blockIdx.x;
    int xcd = bi & 7, idx = bi >> 3;          // idx in [0,64)
    int jgrp = xcd >> 1, whalf = xcd & 1;     // job = (b, t-pair); w-half per XCD
    int b = jgrp >> 1;
    int h2 = idx & 31;                        // h-pair index
    int tsel = (idx >> 5) & 1;                // per-CU light/heavy interleave
    int t = ((jgrp & 1) << 1) + tsel;         // t-pair {0,1} or {2,3}
    int h0 = h2 * 2;
    int wb = whalf * 32;

    int pl = nf * 16 + l15;               // local position 0..63 (2 rows x 32 w)
    int prow = pl >> 5, pcol = pl & 31;
    int hr = h0 + prow;                   // this lane's output h row
    int p  = wb + pcol;                   // global w position
    int cbase = chh * 32 + l4 * 8;        // channel slice (MFMA K slice)
    int ktlo = (t == 0) ? 1 : 0, kthi = (t == 3) ? 2 : 3;

    // init s_off with bias (pad cols junk; never read)
    for (int i = tid; i < KVc * 2 * 66; i += 512) {
        int k = i / 132, rem = i - k * 132, jo = rem / 66;
        s_off[i] = obias[2 * k + jo];
    }

    const __hip_bfloat16* xb = src + ((size_t)b << 20);

    auto stage = [&](int kt) {
        int tt = t + kt - 1;   // valid by loop range
        const __hip_bfloat16* xt = xb + ((size_t)tt << 18);
        for (int i = tid; i < 6 * WT * 8; i += 512) {
            int r = i / (WT * 8), v = i - r * (WT * 8);
            int wl = v >> 3, ss = v & 7;
            int hh = h0 - 2 + r;
            int wg = wb - 3 + wl;
            bf16x8 val = {0, 0, 0, 0, 0, 0, 0, 0};
            if ((unsigned)hh < 64u && (unsigned)wg < 64u)
                val = *reinterpret_cast<const bf16x8*>(xt + ((hh * 64 + wg) << 6) + ss * 8);
            int byte = (r * RSTRIDE + wl * 128 + ss * 16) ^ ((wl & 7) << 4);
            *reinterpret_cast<bf16x8*>((char*)s_tile + byte) = val;
        }
    };
    auto ldread = [&](int sl, int wg) -> bf16x8 {   // wg = clamped global w (in window)
        int wl = wg - (wb - 3);
        int byte = (sl * RSTRIDE + wl * 128 + cbase * 2) ^ ((wl & 7) << 4);
        return *reinterpret_cast<const bf16x8*>((const char*)s_tile + byte);
    };

    // ================= pass A: offset conv (rolled taps) =================
    f32x4 cacc[4];
    #pragma unroll
    for (int mf = 0; mf < 4; ++mf) cacc[mf] = (f32x4){0.f, 0.f, 0.f, 0.f};

    for (int kt = ktlo; kt < kthi; ++kt) {
        __syncthreads();
        stage(kt);
        __syncthreads();
        #pragma clang loop unroll(disable)
        for (int rr = 0; rr < 9; ++rr) {
            int kh = rr / 3, kw = rr - kh * 3, tap = kt * 9 + rr;
            int ws = p + kw - 1;
            int wsc = min(max(ws, 0), 63);
            bf16x8 bv = ldread(prow + kh + 1, wsc);   // rows h0-1..h0+3 -> tile 1..4(+prow)
            if ((unsigned)ws >= 64u) bv = (bf16x8){0, 0, 0, 0, 0, 0, 0, 0};
            const __hip_bfloat16* ab = owAk + ((tap * 2 + chh) << 11) + (l15 << 5) + (l4 << 3);
            #pragma unroll
            for (int mf = 0; mf < 4; ++mf) {
                bf16x8 af = *reinterpret_cast<const bf16x8*>(ab + (mf << 9));
                cacc[mf] = __builtin_amdgcn_mfma_f32_16x16x32_bf16(af, bv, cacc[mf], 0, 0, 0);
            }
        }
    }
    #pragma unroll
    for (int mf = 0; mf < 4; ++mf)
        #pragma unroll
        for (int jj = 0; jj < 4; ++jj) {
            int o = mf * 16 + l4 * 4 + jj;
            if (o < OFFc) atomicAdd(&s_off[(o >> 1) * 132 + (o & 1) * 66 + pl], cacc[mf][jj]);
        }

    // ================= pass B: deformable conv (rolled x2, reverse kt) =================
    f32x4 dacc[4];
    #pragma unroll
    for (int mf = 0; mf < 4; ++mf) dacc[mf] = (f32x4){0.f, 0.f, 0.f, 0.f};

    unsigned badmask = 0;

    for (int kt = kthi - 1; kt >= ktlo; --kt) {
        __syncthreads();     // first iter: guards s_off atomics; tile already holds kthi-1
        if (kt != kthi - 1) {
            stage(kt);
            __syncthreads();
        }
        #pragma clang loop unroll_count(2)
        for (int rr = 0; rr < 9; ++rr) {
            int kh = rr / 3, kw = rr - kh * 3, tap = kt * 9 + rr;
            float dh = s_off[tap * 132 + pl];
            float dw = s_off[tap * 132 + 66 + pl];
            float hs  = (float)(hr + kh - 1) + dh;
            float wsf = (float)(p + kw - 1) + dw;
            float fh = floorf(hs), fw = floorf(wsf);
            int hfl = (int)fh, w0 = (int)fw;
            float lh = hs - fh, lw = wsf - fw;
            float q0 = (1.f - lw) * (((unsigned)w0 < 64u) ? 1.f : 0.f);
            float q1 = lw         * (((unsigned)(w0 + 1) < 64u) ? 1.f : 0.f);
            int wc0 = min(max(w0, 0), 63), wc1 = min(max(w0 + 1, 0), 63);
            int r0 = hfl - (h0 - 2);
            int r0c = min(max(r0, 0), 4);
            badmask |= ((r0 != r0c) ? 1u : 0u) << tap;
            bf16x8 g0 = ldread(r0c, wc0),     g1 = ldread(r0c, wc1);
            bf16x8 g2 = ldread(r0c + 1, wc0), g3 = ldread(r0c + 1, wc1);
            float cf0 = (1.f - lh) * q0, cf1 = (1.f - lh) * q1;
            float cf2 = lh * q0,         cf3 = lh * q1;
            bf16x8 bfrag;
            #pragma unroll
            for (int jj = 0; jj < 8; ++jj) {
                float s = cf0 * bf2f(g0[jj]) + cf1 * bf2f(g1[jj])
                        + cf2 * bf2f(g2[jj]) + cf3 * bf2f(g3[jj]);
                bfrag[jj] = f2bf(s);
            }
            const __hip_bfloat16* ab = wAk + ((tap * 2 + chh) << 11) + (l15 << 5) + (l4 << 3);
            #pragma unroll
            for (int mf = 0; mf < 4; ++mf) {
                bf16x8 af = *reinterpret_cast<const bf16x8*>(ab + (mf << 9));
                dacc[mf] = __builtin_amdgcn_mfma_f32_16x16x32_bf16(af, bfrag, dacc[mf], 0, 0, 0);
            }
        }
    }

    // ---- exact correction for window misses (cold; never taken for ~0.02-scale offsets) ----
    if (__any((int)(badmask != 0u))) {
        for (int kt = ktlo; kt < kthi; ++kt) {
            int tt = t + kt - 1;
            const __hip_bfloat16* xt = xb + ((size_t)tt << 18);
            #pragma clang loop unroll(disable)
            for (int rr = 0; rr < 9; ++rr) {
                int tap = kt * 9 + rr;
                if (!__any((int)((badmask >> tap) & 1u))) continue;
                int kh = rr / 3, kw = rr - kh * 3;
                float dh = s_off[tap * 132 + pl];
                float dw = s_off[tap * 132 + 66 + pl];
                float hs  = (float)(hr + kh - 1) + dh;
                float wsf = (float)(p + kw - 1) + dw;
                float fh = floorf(hs), fw = floorf(wsf);
                int hfl = (int)fh, w0 = (int)fw;
                float lh = hs - fh, lw = wsf - fw;
                float q0 = (1.f - lw) * (((unsigned)w0 < 64u) ? 1.f : 0.f);
                float q1 = lw         * (((unsigned)(w0 + 1) < 64u) ? 1.f : 0.f);
                int wc0 = min(max(w0, 0), 63), wc1 = min(max(w0 + 1, 0), 63);
                int r0 = hfl - (h0 - 2);
                int r0c = min(max(r0, 0), 4);
                bool bad = ((badmask >> tap) & 1u) != 0u;
                float u0 = (1.f - lh) * (((unsigned)hfl < 64u) ? 1.f : 0.f);
                float u1 = lh         * (((unsigned)(hfl + 1) < 64u) ? 1.f : 0.f);
                int hc0 = min(max(hfl, 0), 63), hc1 = min(max(hfl + 1, 0), 63);
                bf16x8 tg0 = *reinterpret_cast<const bf16x8*>(xt + ((hc0 * 64 + wc0) << 6) + cbase);
                bf16x8 tg1 = *reinterpret_cast<const bf16x8*>(xt + ((hc0 * 64 + wc1) << 6) + cbase);
                bf16x8 tg2 = *reinterpret_cast<const bf16x8*>(xt + ((hc1 * 64 + wc0) << 6) + cbase);
                bf16x8 tg3 = *reinterpret_cast<const bf16x8*>(xt + ((hc1 * 64 + wc1) << 6) + cbase);
                int ra0 = h0 - 2 + r0c, ra1 = ra0 + 1;
                float m0 = ((unsigned)ra0 < 64u) ? 1.f : 0.f;
                float m1 = ((unsigned)ra1 < 64u) ? 1.f : 0.f;
                int rc0 = min(max(ra0, 0), 63), rc1 = min(max(ra1, 0), 63);
                bf16x8 ag0 = *reinterpret_cast<const bf16x8*>(xt + ((rc0 * 64 + wc0) << 6) + cbase);
                bf16x8 ag1 = *reinterpret_cast<const bf16x8*>(xt + ((rc0 * 64 + wc1) << 6) + cbase);
                bf16x8 ag2 = *reinterpret_cast<const bf16x8*>(xt + ((rc1 * 64 + wc0) << 6) + cbase);
                bf16x8 ag3 = *reinterpret_cast<const bf16x8*>(xt + ((rc1 * 64 + wc1) << 6) + cbase);
                bf16x8 bfrag;
                #pragma unroll
                for (int jj = 0; jj < 8; ++jj) {
                    float ft = u0 * (q0 * bf2f(tg0[jj]) + q1 * bf2f(tg1[jj]))
                             + u1 * (q0 * bf2f(tg2[jj]) + q1 * bf2f(tg3[jj]));
                    float fa = (1.f - lh) * m0 * (q0 * bf2f(ag0[jj]) + q1 * bf2f(ag1[jj]))
                             + lh * m1 * (q0 * bf2f(ag2[jj]) + q1 * bf2f(ag3[jj]));
                    bfrag[jj] = f2bf(bad ? (ft - fa) : 0.f);
                }
                const __hip_bfloat16* ab = wAk + ((tap * 2 + chh) << 11) + (l15 << 5) + (l4 << 3);
                #pragma unroll
                for (int mf = 0; mf < 4; ++mf) {
                    bf16x8 af = *reinterpret_cast<const bf16x8*>(ab + (mf << 9));
                    dacc[mf] = __builtin_amdgcn_mfma_f32_16x16x32_bf16(af, bfrag, dacc[mf], 0, 0, 0);
                }
            }
        }
    }

    // ---- reduce: s_red aliased onto tile ----
    __syncthreads();
    for (int i = tid; i < 64 * 68; i += 512) s_red[i] = 0.f;
    __syncthreads();
    #pragma unroll
    for (int mf = 0; mf < 4; ++mf)
        #pragma unroll
        for (int jj = 0; jj < 4; ++jj) {
            int o = mf * 16 + l4 * 4 + jj;
            atomicAdd(&s_red[pl * 68 + o], dacc[mf][jj]);
        }
    __syncthreads();

    // ---- fused epilogue ----
    if (!L2) {
        // leaky-relu + channel-last bf16 store (64 pos x 64 ch)
        int pp = tid >> 3, o8 = (tid & 7) << 3;
        int er = pp >> 5, ew = pp & 31;
        __hip_bfloat16* dst = ycl + ((((size_t)b * Tc + t) * HW + (h0 + er) * 64 + wb + ew) << 6) + o8;
        bf16x8 o8v;
        #pragma unroll
        for (int jj = 0; jj < 8; ++jj) {
            float v = s_red[pp * 68 + o8 + jj];
            v = v >= 0.f ? v : 0.1f * v;
            o8v[jj] = f2bf(v);
        }
        *reinterpret_cast<bf16x8*>(dst) = o8v;
    } else {
        // residual add + fp32 channel-first store
        int o = tid >> 3, pg = (tid & 7) << 3;   // 8 positions per thread, same row
        int er = pg >> 5, ew = pg & 31;
        size_t base = ((size_t)(b * Cc + o) * Tc + t) * HW + (h0 + er) * 64 + wb + ew;
        #pragma unroll
        for (int q = 0; q < 2; ++q) {
            f32x4 r, xv = *reinterpret_cast<const f32x4*>(xres + base + q * 4);
            #pragma unroll
            for (int jj = 0; jj < 4; ++jj) r[jj] = s_red[(pg + q * 4 + jj) * 68 + o] + xv[jj];
            *reinterpret_cast<f32x4*>(outf + base + q * 4) = r;
        }
    }
}

extern "C" void kernel_launch(void* const* d_in, const int* in_sizes, int n_in,
                              void* d_out, int out_size, void* d_ws, size_t ws_size,
                              hipStream_t stream)
{
    const float* x   = (const float*)d_in[0];
    const float* w0  = (const float*)d_in[1];
    const float* ow0 = (const float*)d_in[2];
    const float* ob0 = (const float*)d_in[3];
    const float* w1  = (const float*)d_in[4];
    const float* ow1 = (const float*)d_in[5];
    const float* ob1 = (const float*)d_in[6];
    float* out = (float*)d_out;

    __hip_bfloat16* xcl  = (__hip_bfloat16*)d_ws;
    __hip_bfloat16* ycl  = xcl  + (size_t)Bc * THW * 64;
    __hip_bfloat16* owA0 = ycl  + (size_t)Bc * THW * 64;
    __hip_bfloat16* owA1 = owA0 + (size_t)216 * 512;
    __hip_bfloat16* wA0  = owA1 + (size_t)216 * 512;
    __hip_bfloat16* wA1  = wA0  + (size_t)216 * 512;

    w_prep4<<<1728, 256, 0, stream>>>(ow0, ow1, w0, w1, owA0, owA1, wA0, wA1);
    cast_cl<<<512, 256, 0, stream>>>(x, xcl);

    fused_deform<false><<<512, 512, 0, stream>>>(xcl, owA0, ob0, wA0, nullptr, nullptr, ycl);
    fused_deform<true><<<512, 512, 0, stream>>>(ycl, owA1, ob1, wA1, x, out, nullptr);
}

// Round 25
// 143.695 us; speedup vs baseline: 1.2882x; 1.2812x over previous
//
#include <hip/hip_runtime.h>
#include <hip/hip_bf16.h>

#define DEVI __device__ __forceinline__

constexpr int Bc = 2, Cc = 64, Tc = 4, Hc = 64, Wc = 64, OFFc = 54, KVc = 27;
constexpr int HW  = Hc * Wc;     // 4096
constexpr int THW = Tc * HW;     // 16384

typedef __attribute__((ext_vector_type(8))) short bf16x8;
typedef __attribute__((ext_vector_type(4))) float f32x4;

DEVI short f2bf(float f) {
    __hip_bfloat16 h = __float2bfloat16(f);
    return *reinterpret_cast<short*>(&h);
}
DEVI float bf2f(short s) {
    unsigned u = ((unsigned)(unsigned short)s) << 16;
    float f; __builtin_memcpy(&f, &u, 4); return f;
}

// ------- all 4 weight buffers -> K-major MFMA A layout, one dispatch -------
__global__ __launch_bounds__(256) void w_prep4(
    const float* __restrict__ w0, const float* __restrict__ w1,
    const float* __restrict__ w2, const float* __restrict__ w3,
    __hip_bfloat16* __restrict__ d0, __hip_bfloat16* __restrict__ d1,
    __hip_bfloat16* __restrict__ d2, __hip_bfloat16* __restrict__ d3)
{
    int gi = blockIdx.x;
    int seg = gi / 432;
    int i = (gi - seg * 432) * 256 + threadIdx.x;   // 216*512 = 110592
    if (i >= 216 * 512) return;
    const float* w = seg == 0 ? w0 : seg == 1 ? w1 : seg == 2 ? w2 : w3;
    __hip_bfloat16* dst = seg == 0 ? d0 : seg == 1 ? d1 : seg == 2 ? d2 : d3;
    int ovalid = (seg < 2) ? OFFc : Cc;
    int u = i >> 9, r = i & 511;
    int mf = u & 3, ch = (u >> 2) & 1, tap = u >> 3;
    int o = mf * 16 + (r >> 5), c = ch * 32 + (r & 31);
    float v = (o < ovalid) ? w[(o * Cc + c) * KVc + tap] : 0.f;
    dst[i] = __float2bfloat16(v);
}

// ------- cast + transpose to channel-last bf16 -------
__global__ __launch_bounds__(256) void cast_cl(const float* __restrict__ x,
                                               __hip_bfloat16* __restrict__ xcl) {
    __shared__ float s[64][65];
    int tid = threadIdx.x;
    int bi  = blockIdx.x;
    int h = bi & 63, t = (bi >> 6) & 3, b = bi >> 8;

    const float* xp = x + (size_t)b * Cc * THW + t * HW + h * 64;
    int w0 = tid & 63, c0 = tid >> 6;
    #pragma unroll
    for (int i = 0; i < 16; ++i) {
        int c = c0 + i * 4;
        s[c][w0] = xp[(size_t)c * THW + w0];
    }
    __syncthreads();

    __hip_bfloat16* dst = xcl + (((size_t)b * Tc + t) * HW + (size_t)h * 64) * 64;
    #pragma unroll
    for (int r = 0; r < 2; ++r) {
        int j  = tid + r * 256;
        int w  = j >> 3;
        int c8 = j & 7;
        bf16x8 v;
        #pragma unroll
        for (int jj = 0; jj < 8; ++jj)
            v[jj] = f2bf(s[c8 * 8 + jj][w]);
        *reinterpret_cast<bf16x8*>(dst + w * 64 + c8 * 8) = v;
    }
}

// ========= fused offset-conv + deformable-conv, 2-row blocks, atomic-free s_red =========
// Geometry identical to R24 (proven 93.5us): block = (b,t,h-pair,whalf), 64 positions,
// 512 thr = 8 waves = nf(4) x chh(2); balanced adjacent-t pairing per XCD.
// CHANGE: final reduction is atomic-free — each chh-half plain-writes its partials to a
// private [64][68] region (each (pl,o) owned by one lane), epilogue sums both regions.
// Removes ~8K lane-RMW LDS atomics + the zero-pass + one barrier per block.
constexpr int WT = 40;            // tile w-columns, covers global w in [wb-3, wb+36]
constexpr int RSTRIDE = WT * 128; // 5120 bytes per tile row

template <bool L2>
__global__ __launch_bounds__(512, 2) void fused_deform(
    const __hip_bfloat16* __restrict__ src, const __hip_bfloat16* __restrict__ owAk,
    const float* __restrict__ obias, const __hip_bfloat16* __restrict__ wAk,
    const float* __restrict__ xres, float* __restrict__ outf,
    __hip_bfloat16* __restrict__ ycl)
{
    __shared__ __align__(16) char s_mem[6 * RSTRIDE + 14256];
    short* s_tile = (short*)s_mem;                    // swizzled tile [6][40][64ch]
    float* s_off  = (float*)(s_mem + 6 * RSTRIDE);    // [27][2][66] f32
    // after pass B + correction: two partial-sum regions alias tile + dead s_off head
    float* red0 = (float*)s_mem;                      // [64][68] chh=0 partials
    float* red1 = (float*)s_mem + 64 * 68;            // [64][68] chh=1 partials

    int tid = threadIdx.x;
    int wv = tid >> 6, lane = tid & 63, l15 = lane & 15, l4 = lane >> 4;
    int nf = wv & 3, chh = wv >> 2;

    // ---- balanced plane-pair -> XCD decode ----
    int bi = blockIdx.x;
    int xcd = bi & 7, idx = bi >> 3;          // idx in [0,64)
    int jgrp = xcd >> 1, whalf = xcd & 1;     // job = (b, t-pair); w-half per XCD
    int b = jgrp >> 1;
    int h2 = idx & 31;                        // h-pair index
    int tsel = (idx >> 5) & 1;                // per-CU light/heavy interleave
    int t = ((jgrp & 1) << 1) + tsel;         // t-pair {0,1} or {2,3}
    int h0 = h2 * 2;
    int wb = whalf * 32;

    int pl = nf * 16 + l15;               // local position 0..63 (2 rows x 32 w)
    int prow = pl >> 5, pcol = pl & 31;
    int hr = h0 + prow;                   // this lane's output h row
    int p  = wb + pcol;                   // global w position
    int cbase = chh * 32 + l4 * 8;        // channel slice (MFMA K slice)
    int ktlo = (t == 0) ? 1 : 0, kthi = (t == 3) ? 2 : 3;

    // init s_off with bias (pad cols junk; never read)
    for (int i = tid; i < KVc * 2 * 66; i += 512) {
        int k = i / 132, rem = i - k * 132, jo = rem / 66;
        s_off[i] = obias[2 * k + jo];
    }

    const __hip_bfloat16* xb = src + ((size_t)b << 20);

    auto stage = [&](int kt) {
        int tt = t + kt - 1;   // valid by loop range
        const __hip_bfloat16* xt = xb + ((size_t)tt << 18);
        for (int i = tid; i < 6 * WT * 8; i += 512) {
            int r = i / (WT * 8), v = i - r * (WT * 8);
            int wl = v >> 3, ss = v & 7;
            int hh = h0 - 2 + r;
            int wg = wb - 3 + wl;
            bf16x8 val = {0, 0, 0, 0, 0, 0, 0, 0};
            if ((unsigned)hh < 64u && (unsigned)wg < 64u)
                val = *reinterpret_cast<const bf16x8*>(xt + ((hh * 64 + wg) << 6) + ss * 8);
            int byte = (r * RSTRIDE + wl * 128 + ss * 16) ^ ((wl & 7) << 4);
            *reinterpret_cast<bf16x8*>((char*)s_tile + byte) = val;
        }
    };
    auto ldread = [&](int sl, int wg) -> bf16x8 {   // wg = clamped global w (in window)
        int wl = wg - (wb - 3);
        int byte = (sl * RSTRIDE + wl * 128 + cbase * 2) ^ ((wl & 7) << 4);
        return *reinterpret_cast<const bf16x8*>((const char*)s_tile + byte);
    };

    // ================= pass A: offset conv (rolled taps) =================
    f32x4 cacc[4];
    #pragma unroll
    for (int mf = 0; mf < 4; ++mf) cacc[mf] = (f32x4){0.f, 0.f, 0.f, 0.f};

    for (int kt = ktlo; kt < kthi; ++kt) {
        __syncthreads();
        stage(kt);
        __syncthreads();
        #pragma clang loop unroll(disable)
        for (int rr = 0; rr < 9; ++rr) {
            int kh = rr / 3, kw = rr - kh * 3, tap = kt * 9 + rr;
            int ws = p + kw - 1;
            int wsc = min(max(ws, 0), 63);
            bf16x8 bv = ldread(prow + kh + 1, wsc);   // rows h0-1..h0+3 -> tile 1..4(+prow)
            if ((unsigned)ws >= 64u) bv = (bf16x8){0, 0, 0, 0, 0, 0, 0, 0};
            const __hip_bfloat16* ab = owAk + ((tap * 2 + chh) << 11) + (l15 << 5) + (l4 << 3);
            #pragma unroll
            for (int mf = 0; mf < 4; ++mf) {
                bf16x8 af = *reinterpret_cast<const bf16x8*>(ab + (mf << 9));
                cacc[mf] = __builtin_amdgcn_mfma_f32_16x16x32_bf16(af, bv, cacc[mf], 0, 0, 0);
            }
        }
    }
    #pragma unroll
    for (int mf = 0; mf < 4; ++mf)
        #pragma unroll
        for (int jj = 0; jj < 4; ++jj) {
            int o = mf * 16 + l4 * 4 + jj;
            if (o < OFFc) atomicAdd(&s_off[(o >> 1) * 132 + (o & 1) * 66 + pl], cacc[mf][jj]);
        }

    // ================= pass B: deformable conv (rolled x2, reverse kt) =================
    f32x4 dacc[4];
    #pragma unroll
    for (int mf = 0; mf < 4; ++mf) dacc[mf] = (f32x4){0.f, 0.f, 0.f, 0.f};

    unsigned badmask = 0;

    for (int kt = kthi - 1; kt >= ktlo; --kt) {
        __syncthreads();     // first iter: guards s_off atomics; tile already holds kthi-1
        if (kt != kthi - 1) {
            stage(kt);
            __syncthreads();
        }
        #pragma clang loop unroll_count(2)
        for (int rr = 0; rr < 9; ++rr) {
            int kh = rr / 3, kw = rr - kh * 3, tap = kt * 9 + rr;
            float dh = s_off[tap * 132 + pl];
            float dw = s_off[tap * 132 + 66 + pl];
            float hs  = (float)(hr + kh - 1) + dh;
            float wsf = (float)(p + kw - 1) + dw;
            float fh = floorf(hs), fw = floorf(wsf);
            int hfl = (int)fh, w0 = (int)fw;
            float lh = hs - fh, lw = wsf - fw;
            float q0 = (1.f - lw) * (((unsigned)w0 < 64u) ? 1.f : 0.f);
            float q1 = lw         * (((unsigned)(w0 + 1) < 64u) ? 1.f : 0.f);
            int wc0 = min(max(w0, 0), 63), wc1 = min(max(w0 + 1, 0), 63);
            int r0 = hfl - (h0 - 2);
            int r0c = min(max(r0, 0), 4);
            badmask |= ((r0 != r0c) ? 1u : 0u) << tap;
            bf16x8 g0 = ldread(r0c, wc0),     g1 = ldread(r0c, wc1);
            bf16x8 g2 = ldread(r0c + 1, wc0), g3 = ldread(r0c + 1, wc1);
            float cf0 = (1.f - lh) * q0, cf1 = (1.f - lh) * q1;
            float cf2 = lh * q0,         cf3 = lh * q1;
            bf16x8 bfrag;
            #pragma unroll
            for (int jj = 0; jj < 8; ++jj) {
                float s = cf0 * bf2f(g0[jj]) + cf1 * bf2f(g1[jj])
                        + cf2 * bf2f(g2[jj]) + cf3 * bf2f(g3[jj]);
                bfrag[jj] = f2bf(s);
            }
            const __hip_bfloat16* ab = wAk + ((tap * 2 + chh) << 11) + (l15 << 5) + (l4 << 3);
            #pragma unroll
            for (int mf = 0; mf < 4; ++mf) {
                bf16x8 af = *reinterpret_cast<const bf16x8*>(ab + (mf << 9));
                dacc[mf] = __builtin_amdgcn_mfma_f32_16x16x32_bf16(af, bfrag, dacc[mf], 0, 0, 0);
            }
        }
    }

    // ---- exact correction for window misses (cold; never taken for ~0.02-scale offsets) ----
    if (__any((int)(badmask != 0u))) {
        for (int kt = ktlo; kt < kthi; ++kt) {
            int tt = t + kt - 1;
            const __hip_bfloat16* xt = xb + ((size_t)tt << 18);
            #pragma clang loop unroll(disable)
            for (int rr = 0; rr < 9; ++rr) {
                int tap = kt * 9 + rr;
                if (!__any((int)((badmask >> tap) & 1u))) continue;
                int kh = rr / 3, kw = rr - kh * 3;
                float dh = s_off[tap * 132 + pl];
                float dw = s_off[tap * 132 + 66 + pl];
                float hs  = (float)(hr + kh - 1) + dh;
                float wsf = (float)(p + kw - 1) + dw;
                float fh = floorf(hs), fw = floorf(wsf);
                int hfl = (int)fh, w0 = (int)fw;
                float lh = hs - fh, lw = wsf - fw;
                float q0 = (1.f - lw) * (((unsigned)w0 < 64u) ? 1.f : 0.f);
                float q1 = lw         * (((unsigned)(w0 + 1) < 64u) ? 1.f : 0.f);
                int wc0 = min(max(w0, 0), 63), wc1 = min(max(w0 + 1, 0), 63);
                int r0 = hfl - (h0 - 2);
                int r0c = min(max(r0, 0), 4);
                bool bad = ((badmask >> tap) & 1u) != 0u;
                float u0 = (1.f - lh) * (((unsigned)hfl < 64u) ? 1.f : 0.f);
                float u1 = lh         * (((unsigned)(hfl + 1) < 64u) ? 1.f : 0.f);
                int hc0 = min(max(hfl, 0), 63), hc1 = min(max(hfl + 1, 0), 63);
                bf16x8 tg0 = *reinterpret_cast<const bf16x8*>(xt + ((hc0 * 64 + wc0) << 6) + cbase);
                bf16x8 tg1 = *reinterpret_cast<const bf16x8*>(xt + ((hc0 * 64 + wc1) << 6) + cbase);
                bf16x8 tg2 = *reinterpret_cast<const bf16x8*>(xt + ((hc1 * 64 + wc0) << 6) + cbase);
                bf16x8 tg3 = *reinterpret_cast<const bf16x8*>(xt + ((hc1 * 64 + wc1) << 6) + cbase);
                int ra0 = h0 - 2 + r0c, ra1 = ra0 + 1;
                float m0 = ((unsigned)ra0 < 64u) ? 1.f : 0.f;
                float m1 = ((unsigned)ra1 < 64u) ? 1.f : 0.f;
                int rc0 = min(max(ra0, 0), 63), rc1 = min(max(ra1, 0), 63);
                bf16x8 ag0 = *reinterpret_cast<const bf16x8*>(xt + ((rc0 * 64 + wc0) << 6) + cbase);
                bf16x8 ag1 = *reinterpret_cast<const bf16x8*>(xt + ((rc0 * 64 + wc1) << 6) + cbase);
                bf16x8 ag2 = *reinterpret_cast<const bf16x8*>(xt + ((rc1 * 64 + wc0) << 6) + cbase);
                bf16x8 ag3 = *reinterpret_cast<const bf16x8*>(xt + ((rc1 * 64 + wc1) << 6) + cbase);
                bf16x8 bfrag;
                #pragma unroll
                for (int jj = 0; jj < 8; ++jj) {
                    float ft = u0 * (q0 * bf2f(tg0[jj]) + q1 * bf2f(tg1[jj]))
                             + u1 * (q0 * bf2f(tg2[jj]) + q1 * bf2f(tg3[jj]));
                    float fa = (1.f - lh) * m0 * (q0 * bf2f(ag0[jj]) + q1 * bf2f(ag1[jj]))
                             + lh * m1 * (q0 * bf2f(ag2[jj]) + q1 * bf2f(ag3[jj]));
                    bfrag[jj] = f2bf(bad ? (ft - fa) : 0.f);
                }
                const __hip_bfloat16* ab = wAk + ((tap * 2 + chh) << 11) + (l15 << 5) + (l4 << 3);
                #pragma unroll
                for (int mf = 0; mf < 4; ++mf) {
                    bf16x8 af = *reinterpret_cast<const bf16x8*>(ab + (mf << 9));
                    dacc[mf] = __builtin_amdgcn_mfma_f32_16x16x32_bf16(af, bfrag, dacc[mf], 0, 0, 0);
                }
            }
        }
    }

    // ---- atomic-free reduce: per-chh partial regions (tile + s_off head are dead) ----
    __syncthreads();                       // all tile / s_off reads complete
    {
        float* red = chh ? red1 : red0;
        #pragma unroll
        for (int mf = 0; mf < 4; ++mf)
            #pragma unroll
            for (int jj = 0; jj < 4; ++jj) {
                int o = mf * 16 + l4 * 4 + jj;
                red[pl * 68 + o] = dacc[mf][jj];
            }
    }
    __syncthreads();

    // ---- fused epilogue (sum the two chh regions) ----
    if (!L2) {
        // leaky-relu + channel-last bf16 store (64 pos x 64 ch)
        int pp = tid >> 3, o8 = (tid & 7) << 3;
        int er = pp >> 5, ew = pp & 31;
        __hip_bfloat16* dst = ycl + ((((size_t)b * Tc + t) * HW + (h0 + er) * 64 + wb + ew) << 6) + o8;
        bf16x8 o8v;
        #pragma unroll
        for (int jj = 0; jj < 8; ++jj) {
            int i = pp * 68 + o8 + jj;
            float v = red0[i] + red1[i];
            v = v >= 0.f ? v : 0.1f * v;
            o8v[jj] = f2bf(v);
        }
        *reinterpret_cast<bf16x8*>(dst) = o8v;
    } else {
        // residual add + fp32 channel-first store
        int o = tid >> 3, pg = (tid & 7) << 3;   // 8 positions per thread, same row
        int er = pg >> 5, ew = pg & 31;
        size_t base = ((size_t)(b * Cc + o) * Tc + t) * HW + (h0 + er) * 64 + wb + ew;
        #pragma unroll
        for (int q = 0; q < 2; ++q) {
            f32x4 r, xv = *reinterpret_cast<const f32x4*>(xres + base + q * 4);
            #pragma unroll
            for (int jj = 0; jj < 4; ++jj) {
                int i = (pg + q * 4 + jj) * 68 + o;
                r[jj] = red0[i] + red1[i] + xv[jj];
            }
            *reinterpret_cast<f32x4*>(outf + base + q * 4) = r;
        }
    }
}

extern "C" void kernel_launch(void* const* d_in, const int* in_sizes, int n_in,
                              void* d_out, int out_size, void* d_ws, size_t ws_size,
                              hipStream_t stream)
{
    const float* x   = (const float*)d_in[0];
    const float* w0  = (const float*)d_in[1];
    const float* ow0 = (const float*)d_in[2];
    const float* ob0 = (const float*)d_in[3];
    const float* w1  = (const float*)d_in[4];
    const float* ow1 = (const float*)d_in[5];
    const float* ob1 = (const float*)d_in[6];
    float* out = (float*)d_out;

    __hip_bfloat16* xcl  = (__hip_bfloat16*)d_ws;
    __hip_bfloat16* ycl  = xcl  + (size_t)Bc * THW * 64;
    __hip_bfloat16* owA0 = ycl  + (size_t)Bc * THW * 64;
    __hip_bfloat16* owA1 = owA0 + (size_t)216 * 512;
    __hip_bfloat16* wA0  = owA1 + (size_t)216 * 512;
    __hip_bfloat16* wA1  = wA0  + (size_t)216 * 512;

    w_prep4<<<1728, 256, 0, stream>>>(ow0, ow1, w0, w1, owA0, owA1, wA0, wA1);
    cast_cl<<<512, 256, 0, stream>>>(x, xcl);

    fused_deform<false><<<512, 512, 0, stream>>>(xcl, owA0, ob0, wA0, nullptr, nullptr, ycl);
    fused_deform<true><<<512, 512, 0, stream>>>(ycl, owA1, ob1, wA1, x, out, nullptr);
}

// Round 26
// 114.774 us; speedup vs baseline: 1.6128x; 1.2520x over previous
//
#include <hip/hip_runtime.h>
#include <hip/hip_bf16.h>

#define DEVI __device__ __forceinline__

constexpr int Bc = 2, Cc = 64, Tc = 4, Hc = 64, Wc = 64, OFFc = 54, KVc = 27;
constexpr int HW  = Hc * Wc;     // 4096
constexpr int THW = Tc * HW;     // 16384

typedef __attribute__((ext_vector_type(8))) short bf16x8;
typedef __attribute__((ext_vector_type(4))) float f32x4;

DEVI short f2bf(float f) {
    __hip_bfloat16 h = __float2bfloat16(f);
    return *reinterpret_cast<short*>(&h);
}
DEVI float bf2f(short s) {
    unsigned u = ((unsigned)(unsigned short)s) << 16;
    float f; __builtin_memcpy(&f, &u, 4); return f;
}

// ------- all 4 weight buffers -> K-major MFMA A layout, one dispatch -------
__global__ __launch_bounds__(256) void w_prep4(
    const float* __restrict__ w0, const float* __restrict__ w1,
    const float* __restrict__ w2, const float* __restrict__ w3,
    __hip_bfloat16* __restrict__ d0, __hip_bfloat16* __restrict__ d1,
    __hip_bfloat16* __restrict__ d2, __hip_bfloat16* __restrict__ d3)
{
    int gi = blockIdx.x;
    int seg = gi / 432;
    int i = (gi - seg * 432) * 256 + threadIdx.x;   // 216*512 = 110592
    if (i >= 216 * 512) return;
    const float* w = seg == 0 ? w0 : seg == 1 ? w1 : seg == 2 ? w2 : w3;
    __hip_bfloat16* dst = seg == 0 ? d0 : seg == 1 ? d1 : seg == 2 ? d2 : d3;
    int ovalid = (seg < 2) ? OFFc : Cc;
    int u = i >> 9, r = i & 511;
    int mf = u & 3, ch = (u >> 2) & 1, tap = u >> 3;
    int o = mf * 16 + (r >> 5), c = ch * 32 + (r & 31);
    float v = (o < ovalid) ? w[(o * Cc + c) * KVc + tap] : 0.f;
    dst[i] = __float2bfloat16(v);
}

// ------- cast + transpose to channel-last bf16 -------
__global__ __launch_bounds__(256) void cast_cl(const float* __restrict__ x,
                                               __hip_bfloat16* __restrict__ xcl) {
    __shared__ float s[64][65];
    int tid = threadIdx.x;
    int bi  = blockIdx.x;
    int h = bi & 63, t = (bi >> 6) & 3, b = bi >> 8;

    const float* xp = x + (size_t)b * Cc * THW + t * HW + h * 64;
    int w0 = tid & 63, c0 = tid >> 6;
    #pragma unroll
    for (int i = 0; i < 16; ++i) {
        int c = c0 + i * 4;
        s[c][w0] = xp[(size_t)c * THW + w0];
    }
    __syncthreads();

    __hip_bfloat16* dst = xcl + (((size_t)b * Tc + t) * HW + (size_t)h * 64) * 64;
    #pragma unroll
    for (int r = 0; r < 2; ++r) {
        int j  = tid + r * 256;
        int w  = j >> 3;
        int c8 = j & 7;
        bf16x8 v;
        #pragma unroll
        for (int jj = 0; jj < 8; ++jj)
            v[jj] = f2bf(s[c8 * 8 + jj][w]);
        *reinterpret_cast<bf16x8*>(dst + w * 64 + c8 * 8) = v;
    }
}

// ===== fused offset-conv + deformable-conv, 2-row blocks, FULLY atomic-free =====
// Geometry identical to R24/R25. CHANGE vs R25: pass A's s_off reduction is also
// atomic-free — each chh-half plain-stores partials to a private [27][2][66] region
// (each (pl,o) owned by one lane), then a 7-iter merge pass sums both + bias into
// canonical s_off (in-place in region 0). Removes the last ~7K LDS RMW atomics/block
// (the s_red equivalent was worth 20us in R25). Bias-init pass deleted too.
constexpr int WT = 40;            // tile w-columns, covers global w in [wb-3, wb+36]
constexpr int RSTRIDE = WT * 128; // 5120 bytes per tile row
constexpr int OFFB = 14256;       // bytes per s_off region ([27][2][66] f32)

template <bool L2>
__global__ __launch_bounds__(512, 2) void fused_deform(
    const __hip_bfloat16* __restrict__ src, const __hip_bfloat16* __restrict__ owAk,
    const float* __restrict__ obias, const __hip_bfloat16* __restrict__ wAk,
    const float* __restrict__ xres, float* __restrict__ outf,
    __hip_bfloat16* __restrict__ ycl)
{
    __shared__ __align__(16) char s_mem[6 * RSTRIDE + 2 * OFFB];
    short* s_tile = (short*)s_mem;                            // swizzled tile [6][40][64ch]
    float* sp0    = (float*)(s_mem + 6 * RSTRIDE);            // chh=0 partials -> canonical s_off
    float* sp1    = (float*)(s_mem + 6 * RSTRIDE + OFFB);     // chh=1 partials
    float* s_off  = sp0;                                      // after merge
    // after pass B + correction: partial-sum regions alias tile (dead by then)
    float* red0 = (float*)s_mem;                              // [64][68] chh=0 partials
    float* red1 = (float*)s_mem + 64 * 68;                    // [64][68] chh=1 partials

    int tid = threadIdx.x;
    int wv = tid >> 6, lane = tid & 63, l15 = lane & 15, l4 = lane >> 4;
    int nf = wv & 3, chh = wv >> 2;

    // ---- balanced plane-pair -> XCD decode ----
    int bi = blockIdx.x;
    int xcd = bi & 7, idx = bi >> 3;          // idx in [0,64)
    int jgrp = xcd >> 1, whalf = xcd & 1;     // job = (b, t-pair); w-half per XCD
    int b = jgrp >> 1;
    int h2 = idx & 31;                        // h-pair index
    int tsel = (idx >> 5) & 1;                // per-CU light/heavy interleave
    int t = ((jgrp & 1) << 1) + tsel;         // t-pair {0,1} or {2,3}
    int h0 = h2 * 2;
    int wb = whalf * 32;

    int pl = nf * 16 + l15;               // local position 0..63 (2 rows x 32 w)
    int prow = pl >> 5, pcol = pl & 31;
    int hr = h0 + prow;                   // this lane's output h row
    int p  = wb + pcol;                   // global w position
    int cbase = chh * 32 + l4 * 8;        // channel slice (MFMA K slice)
    int ktlo = (t == 0) ? 1 : 0, kthi = (t == 3) ? 2 : 3;

    const __hip_bfloat16* xb = src + ((size_t)b << 20);

    auto stage = [&](int kt) {
        int tt = t + kt - 1;   // valid by loop range
        const __hip_bfloat16* xt = xb + ((size_t)tt << 18);
        for (int i = tid; i < 6 * WT * 8; i += 512) {
            int r = i / (WT * 8), v = i - r * (WT * 8);
            int wl = v >> 3, ss = v & 7;
            int hh = h0 - 2 + r;
            int wg = wb - 3 + wl;
            bf16x8 val = {0, 0, 0, 0, 0, 0, 0, 0};
            if ((unsigned)hh < 64u && (unsigned)wg < 64u)
                val = *reinterpret_cast<const bf16x8*>(xt + ((hh * 64 + wg) << 6) + ss * 8);
            int byte = (r * RSTRIDE + wl * 128 + ss * 16) ^ ((wl & 7) << 4);
            *reinterpret_cast<bf16x8*>((char*)s_tile + byte) = val;
        }
    };
    auto ldread = [&](int sl, int wg) -> bf16x8 {   // wg = clamped global w (in window)
        int wl = wg - (wb - 3);
        int byte = (sl * RSTRIDE + wl * 128 + cbase * 2) ^ ((wl & 7) << 4);
        return *reinterpret_cast<const bf16x8*>((const char*)s_tile + byte);
    };

    // ================= pass A: offset conv (rolled taps) =================
    f32x4 cacc[4];
    #pragma unroll
    for (int mf = 0; mf < 4; ++mf) cacc[mf] = (f32x4){0.f, 0.f, 0.f, 0.f};

    for (int kt = ktlo; kt < kthi; ++kt) {
        __syncthreads();
        stage(kt);
        __syncthreads();
        #pragma clang loop unroll(disable)
        for (int rr = 0; rr < 9; ++rr) {
            int kh = rr / 3, kw = rr - kh * 3, tap = kt * 9 + rr;
            int ws = p + kw - 1;
            int wsc = min(max(ws, 0), 63);
            bf16x8 bv = ldread(prow + kh + 1, wsc);   // rows h0-1..h0+3 -> tile 1..4(+prow)
            if ((unsigned)ws >= 64u) bv = (bf16x8){0, 0, 0, 0, 0, 0, 0, 0};
            const __hip_bfloat16* ab = owAk + ((tap * 2 + chh) << 11) + (l15 << 5) + (l4 << 3);
            #pragma unroll
            for (int mf = 0; mf < 4; ++mf) {
                bf16x8 af = *reinterpret_cast<const bf16x8*>(ab + (mf << 9));
                cacc[mf] = __builtin_amdgcn_mfma_f32_16x16x32_bf16(af, bv, cacc[mf], 0, 0, 0);
            }
        }
    }
    // ---- atomic-free s_off reduction: plain stores to per-chh partial region ----
    {
        float* sp = chh ? sp1 : sp0;
        #pragma unroll
        for (int mf = 0; mf < 4; ++mf)
            #pragma unroll
            for (int jj = 0; jj < 4; ++jj) {
                int o = mf * 16 + l4 * 4 + jj;
                if (o < OFFc) sp[(o >> 1) * 132 + (o & 1) * 66 + pl] = cacc[mf][jj];
            }
    }
    __syncthreads();
    // ---- merge: s_off = sp0 + sp1 + bias (7 iters/thread; pad entries garbage, never read)
    for (int i = tid; i < KVc * 2 * 66; i += 512) {
        int k = i / 132, rem = i - k * 132, jo = rem / 66;
        sp0[i] = sp0[i] + sp1[i] + obias[2 * k + jo];
    }

    // ================= pass B: deformable conv (rolled x2, reverse kt) =================
    f32x4 dacc[4];
    #pragma unroll
    for (int mf = 0; mf < 4; ++mf) dacc[mf] = (f32x4){0.f, 0.f, 0.f, 0.f};

    unsigned badmask = 0;

    for (int kt = kthi - 1; kt >= ktlo; --kt) {
        __syncthreads();     // first iter: guards s_off merge; tile already holds kthi-1
        if (kt != kthi - 1) {
            stage(kt);
            __syncthreads();
        }
        #pragma clang loop unroll_count(2)
        for (int rr = 0; rr < 9; ++rr) {
            int kh = rr / 3, kw = rr - kh * 3, tap = kt * 9 + rr;
            float dh = s_off[tap * 132 + pl];
            float dw = s_off[tap * 132 + 66 + pl];
            float hs  = (float)(hr + kh - 1) + dh;
            float wsf = (float)(p + kw - 1) + dw;
            float fh = floorf(hs), fw = floorf(wsf);
            int hfl = (int)fh, w0 = (int)fw;
            float lh = hs - fh, lw = wsf - fw;
            float q0 = (1.f - lw) * (((unsigned)w0 < 64u) ? 1.f : 0.f);
            float q1 = lw         * (((unsigned)(w0 + 1) < 64u) ? 1.f : 0.f);
            int wc0 = min(max(w0, 0), 63), wc1 = min(max(w0 + 1, 0), 63);
            int r0 = hfl - (h0 - 2);
            int r0c = min(max(r0, 0), 4);
            badmask |= ((r0 != r0c) ? 1u : 0u) << tap;
            bf16x8 g0 = ldread(r0c, wc0),     g1 = ldread(r0c, wc1);
            bf16x8 g2 = ldread(r0c + 1, wc0), g3 = ldread(r0c + 1, wc1);
            float cf0 = (1.f - lh) * q0, cf1 = (1.f - lh) * q1;
            float cf2 = lh * q0,         cf3 = lh * q1;
            bf16x8 bfrag;
            #pragma unroll
            for (int jj = 0; jj < 8; ++jj) {
                float s = cf0 * bf2f(g0[jj]) + cf1 * bf2f(g1[jj])
                        + cf2 * bf2f(g2[jj]) + cf3 * bf2f(g3[jj]);
                bfrag[jj] = f2bf(s);
            }
            const __hip_bfloat16* ab = wAk + ((tap * 2 + chh) << 11) + (l15 << 5) + (l4 << 3);
            #pragma unroll
            for (int mf = 0; mf < 4; ++mf) {
                bf16x8 af = *reinterpret_cast<const bf16x8*>(ab + (mf << 9));
                dacc[mf] = __builtin_amdgcn_mfma_f32_16x16x32_bf16(af, bfrag, dacc[mf], 0, 0, 0);
            }
        }
    }

    // ---- exact correction for window misses (cold; never taken for ~0.02-scale offsets) ----
    if (__any((int)(badmask != 0u))) {
        for (int kt = ktlo; kt < kthi; ++kt) {
            int tt = t + kt - 1;
            const __hip_bfloat16* xt = xb + ((size_t)tt << 18);
            #pragma clang loop unroll(disable)
            for (int rr = 0; rr < 9; ++rr) {
                int tap = kt * 9 + rr;
                if (!__any((int)((badmask >> tap) & 1u))) continue;
                int kh = rr / 3, kw = rr - kh * 3;
                float dh = s_off[tap * 132 + pl];
                float dw = s_off[tap * 132 + 66 + pl];
                float hs  = (float)(hr + kh - 1) + dh;
                float wsf = (float)(p + kw - 1) + dw;
                float fh = floorf(hs), fw = floorf(wsf);
                int hfl = (int)fh, w0 = (int)fw;
                float lh = hs - fh, lw = wsf - fw;
                float q0 = (1.f - lw) * (((unsigned)w0 < 64u) ? 1.f : 0.f);
                float q1 = lw         * (((unsigned)(w0 + 1) < 64u) ? 1.f : 0.f);
                int wc0 = min(max(w0, 0), 63), wc1 = min(max(w0 + 1, 0), 63);
                int r0 = hfl - (h0 - 2);
                int r0c = min(max(r0, 0), 4);
                bool bad = ((badmask >> tap) & 1u) != 0u;
                float u0 = (1.f - lh) * (((unsigned)hfl < 64u) ? 1.f : 0.f);
                float u1 = lh         * (((unsigned)(hfl + 1) < 64u) ? 1.f : 0.f);
                int hc0 = min(max(hfl, 0), 63), hc1 = min(max(hfl + 1, 0), 63);
                bf16x8 tg0 = *reinterpret_cast<const bf16x8*>(xt + ((hc0 * 64 + wc0) << 6) + cbase);
                bf16x8 tg1 = *reinterpret_cast<const bf16x8*>(xt + ((hc0 * 64 + wc1) << 6) + cbase);
                bf16x8 tg2 = *reinterpret_cast<const bf16x8*>(xt + ((hc1 * 64 + wc0) << 6) + cbase);
                bf16x8 tg3 = *reinterpret_cast<const bf16x8*>(xt + ((hc1 * 64 + wc1) << 6) + cbase);
                int ra0 = h0 - 2 + r0c, ra1 = ra0 + 1;
                float m0 = ((unsigned)ra0 < 64u) ? 1.f : 0.f;
                float m1 = ((unsigned)ra1 < 64u) ? 1.f : 0.f;
                int rc0 = min(max(ra0, 0), 63), rc1 = min(max(ra1, 0), 63);
                bf16x8 ag0 = *reinterpret_cast<const bf16x8*>(xt + ((rc0 * 64 + wc0) << 6) + cbase);
                bf16x8 ag1 = *reinterpret_cast<const bf16x8*>(xt + ((rc0 * 64 + wc1) << 6) + cbase);
                bf16x8 ag2 = *reinterpret_cast<const bf16x8*>(xt + ((rc1 * 64 + wc0) << 6) + cbase);
                bf16x8 ag3 = *reinterpret_cast<const bf16x8*>(xt + ((rc1 * 64 + wc1) << 6) + cbase);
                bf16x8 bfrag;
                #pragma unroll
                for (int jj = 0; jj < 8; ++jj) {
                    float ft = u0 * (q0 * bf2f(tg0[jj]) + q1 * bf2f(tg1[jj]))
                             + u1 * (q0 * bf2f(tg2[jj]) + q1 * bf2f(tg3[jj]));
                    float fa = (1.f - lh) * m0 * (q0 * bf2f(ag0[jj]) + q1 * bf2f(ag1[jj]))
                             + lh * m1 * (q0 * bf2f(ag2[jj]) + q1 * bf2f(ag3[jj]));
                    bfrag[jj] = f2bf(bad ? (ft - fa) : 0.f);
                }
                const __hip_bfloat16* ab = wAk + ((tap * 2 + chh) << 11) + (l15 << 5) + (l4 << 3);
                #pragma unroll
                for (int mf = 0; mf < 4; ++mf) {
                    bf16x8 af = *reinterpret_cast<const bf16x8*>(ab + (mf << 9));
                    dacc[mf] = __builtin_amdgcn_mfma_f32_16x16x32_bf16(af, bfrag, dacc[mf], 0, 0, 0);
                }
            }
        }
    }

    // ---- atomic-free reduce: per-chh partial regions (tile + s_off dead) ----
    __syncthreads();                       // all tile / s_off reads complete
    {
        float* red = chh ? red1 : red0;
        #pragma unroll
        for (int mf = 0; mf < 4; ++mf)
            #pragma unroll
            for (int jj = 0; jj < 4; ++jj) {
                int o = mf * 16 + l4 * 4 + jj;
                red[pl * 68 + o] = dacc[mf][jj];
            }
    }
    __syncthreads();

    // ---- fused epilogue (sum the two chh regions) ----
    if (!L2) {
        // leaky-relu + channel-last bf16 store (64 pos x 64 ch)
        int pp = tid >> 3, o8 = (tid & 7) << 3;
        int er = pp >> 5, ew = pp & 31;
        __hip_bfloat16* dst = ycl + ((((size_t)b * Tc + t) * HW + (h0 + er) * 64 + wb + ew) << 6) + o8;
        bf16x8 o8v;
        #pragma unroll
        for (int jj = 0; jj < 8; ++jj) {
            int i = pp * 68 + o8 + jj;
            float v = red0[i] + red1[i];
            v = v >= 0.f ? v : 0.1f * v;
            o8v[jj] = f2bf(v);
        }
        *reinterpret_cast<bf16x8*>(dst) = o8v;
    } else {
        // residual add + fp32 channel-first store
        int o = tid >> 3, pg = (tid & 7) << 3;   // 8 positions per thread, same row
        int er = pg >> 5, ew = pg & 31;
        size_t base = ((size_t)(b * Cc + o) * Tc + t) * HW + (h0 + er) * 64 + wb + ew;
        #pragma unroll
        for (int q = 0; q < 2; ++q) {
            f32x4 r, xv = *reinterpret_cast<const f32x4*>(xres + base + q * 4);
            #pragma unroll
            for (int jj = 0; jj < 4; ++jj) {
                int i = (pg + q * 4 + jj) * 68 + o;
                r[jj] = red0[i] + red1[i] + xv[jj];
            }
            *reinterpret_cast<f32x4*>(outf + base + q * 4) = r;
        }
    }
}

extern "C" void kernel_launch(void* const* d_in, const int* in_sizes, int n_in,
                              void* d_out, int out_size, void* d_ws, size_t ws_size,
                              hipStream_t stream)
{
    const float* x   = (const float*)d_in[0];
    const float* w0  = (const float*)d_in[1];
    const float* ow0 = (const float*)d_in[2];
    const float* ob0 = (const float*)d_in[3];
    const float* w1  = (const float*)d_in[4];
    const float* ow1 = (const float*)d_in[5];
    const float* ob1 = (const float*)d_in[6];
    float* out = (float*)d_out;

    __hip_bfloat16* xcl  = (__hip_bfloat16*)d_ws;
    __hip_bfloat16* ycl  = xcl  + (size_t)Bc * THW * 64;
    __hip_bfloat16* owA0 = ycl  + (size_t)Bc * THW * 64;
    __hip_bfloat16* owA1 = owA0 + (size_t)216 * 512;
    __hip_bfloat16* wA0  = owA1 + (size_t)216 * 512;
    __hip_bfloat16* wA1  = wA0  + (size_t)216 * 512;

    w_prep4<<<1728, 256, 0, stream>>>(ow0, ow1, w0, w1, owA0, owA1, wA0, wA1);
    cast_cl<<<512, 256, 0, stream>>>(x, xcl);

    fused_deform<false><<<512, 512, 0, stream>>>(xcl, owA0, ob0, wA0, nullptr, nullptr, ycl);
    fused_deform<true><<<512, 512, 0, stream>>>(ycl, owA1, ob1, wA1, x, out, nullptr);
}